// Round 7
// baseline (480.230 us; speedup 1.0000x reference)
//
#include <hip/hip_runtime.h>
#include <hip/hip_bf16.h>

// Problem constants
#define BB 4
#define SS 2048
#define DD 1024
#define HH 16
#define DKK 64

typedef __attribute__((ext_vector_type(8))) short short8;
typedef __attribute__((ext_vector_type(4))) float f32x4;

typedef const __attribute__((address_space(1))) void gvoid;
typedef __attribute__((address_space(3))) void lvoid;

__device__ __forceinline__ unsigned short f2bf(float f) {
  unsigned int u = __builtin_bit_cast(unsigned int, f);
  u = (u + 0x7FFFu + ((u >> 16) & 1u)) >> 16;
  return (unsigned short)u;
}

// ---------------------------------------------------------------- converts
__global__ __launch_bounds__(256) void convert_f32_bf16(
    const float* __restrict__ in, unsigned short* __restrict__ out, int n4) {
  int i = blockIdx.x * blockDim.x + threadIdx.x;
  if (i >= n4) return;
  float4 v = reinterpret_cast<const float4*>(in)[i];
  ushort4 o;
  o.x = f2bf(v.x); o.y = f2bf(v.y); o.z = f2bf(v.z); o.w = f2bf(v.w);
  reinterpret_cast<ushort4*>(out)[i] = o;
}

// 4 weight matrices -> contiguous bf16 [wq|wk|wv|wo]
__global__ __launch_bounds__(256) void convert_w4(
    const float* __restrict__ a, const float* __restrict__ b,
    const float* __restrict__ c, const float* __restrict__ d,
    unsigned short* __restrict__ out, int n4) {
  int m = blockIdx.y;
  const float* src = (m == 0) ? a : (m == 1) ? b : (m == 2) ? c : d;
  int i = blockIdx.x * blockDim.x + threadIdx.x;
  if (i >= n4) return;
  float4 v = reinterpret_cast<const float4*>(src)[i];
  ushort4 o;
  o.x = f2bf(v.x); o.y = f2bf(v.y); o.z = f2bf(v.z); o.w = f2bf(v.w);
  reinterpret_cast<ushort4*>(out)[(size_t)m * n4 + i] = o;
}

// ---------------------------------------------------------------- merged QKV GEMM
// C = x[8192,1024] * Wcat[3072,1024]^T ; n-tile selects matrix (Q/K/V).
// Q scaled by 1/sqrt(DK)*log2e, scattered to [b,h,s,dk]; K scattered to
// [b,h,s,dk]; V scattered transposed to [b,h,dk,s].
__global__ __launch_bounds__(256) void gemm_qkv(
    const unsigned short* __restrict__ A,
    const unsigned short* __restrict__ Bm,
    unsigned short* __restrict__ Qo,
    unsigned short* __restrict__ Ko,
    unsigned short* __restrict__ Vo)
{
  __shared__ unsigned short As[128 * 32];
  __shared__ unsigned short Bs[128 * 32];
  const int K = DD;
  int bid = blockIdx.x;
  int m0 = (bid / 24) << 7;
  int n0 = (bid % 24) << 7;
  int t = threadIdx.x;
  int lane = t & 63, w = t >> 6;
  int l16 = lane & 15, lhi = lane >> 4;
  int wm = (w >> 1) * 64, wn = (w & 1) * 64;

  f32x4 acc[4][4];
#pragma unroll
  for (int i = 0; i < 4; ++i)
#pragma unroll
    for (int j = 0; j < 4; ++j) acc[i][j] = (f32x4){0.f, 0.f, 0.f, 0.f};

  for (int kt = 0; kt < K; kt += 32) {
    __syncthreads();
#pragma unroll
    for (int is = 0; is < 2; ++is) {
      int c = is * 256 + t;
      __builtin_amdgcn_global_load_lds(
          (gvoid*)(A + (size_t)(m0 + (c >> 2)) * K + kt + ((c & 3) << 3)),
          (lvoid*)(As + (size_t)(is * 256 + w * 64) * 8), 16, 0, 0);
      __builtin_amdgcn_global_load_lds(
          (gvoid*)(Bm + (size_t)(n0 + (c >> 2)) * K + kt + ((c & 3) << 3)),
          (lvoid*)(Bs + (size_t)(is * 256 + w * 64) * 8), 16, 0, 0);
    }
    __syncthreads();
    short8 af[4], bfr[4];
#pragma unroll
    for (int mf = 0; mf < 4; ++mf)
      af[mf] = *(const short8*)(As + (wm + mf * 16 + l16) * 32 + lhi * 8);
#pragma unroll
    for (int nf = 0; nf < 4; ++nf)
      bfr[nf] = *(const short8*)(Bs + (wn + nf * 16 + l16) * 32 + lhi * 8);
#pragma unroll
    for (int mf = 0; mf < 4; ++mf)
#pragma unroll
      for (int nf = 0; nf < 4; ++nf)
        acc[mf][nf] = __builtin_amdgcn_mfma_f32_16x16x32_bf16(
            af[mf], bfr[nf], acc[mf][nf], 0, 0, 0);
  }

  int mat = n0 >> 10;        // 0=Q 1=K 2=V (tile never straddles: 1024%128==0)
  int nb = n0 & 1023;
  const float qscale = 0.18033688011112042f;  // 0.125 * log2(e)
#pragma unroll
  for (int mf = 0; mf < 4; ++mf)
#pragma unroll
    for (int nf = 0; nf < 4; ++nf)
#pragma unroll
      for (int i = 0; i < 4; ++i) {
        int r = m0 + wm + mf * 16 + lhi * 4 + i;
        int c1 = nb + wn + nf * 16 + l16;
        int b = r >> 11, s = r & 2047;
        int h = c1 >> 6, dk = c1 & 63;
        if (mat == 0)
          Qo[((size_t)((b * HH + h) * SS + s) << 6) + dk] =
              f2bf(acc[mf][nf][i] * qscale);
        else if (mat == 1)
          Ko[((size_t)((b * HH + h) * SS + s) << 6) + dk] = f2bf(acc[mf][nf][i]);
        else
          Vo[(size_t)((b * HH + h) * DKK + dk) * SS + s] = f2bf(acc[mf][nf][i]);
      }
}

// ---------------------------------------------------------------- WO GEMM (fp32 out)
__global__ __launch_bounds__(256) void gemm_wo(
    const unsigned short* __restrict__ A,
    const unsigned short* __restrict__ Bm,
    float* __restrict__ C, int N, int K)
{
  __shared__ unsigned short As[128 * 32];
  __shared__ unsigned short Bs[128 * 32];
  int bid = blockIdx.x;
  int ntn = N >> 7;
  int m0 = (bid / ntn) << 7;
  int n0 = (bid % ntn) << 7;
  int t = threadIdx.x;
  int lane = t & 63, w = t >> 6;
  int l16 = lane & 15, lhi = lane >> 4;
  int wm = (w >> 1) * 64, wn = (w & 1) * 64;

  f32x4 acc[4][4];
#pragma unroll
  for (int i = 0; i < 4; ++i)
#pragma unroll
    for (int j = 0; j < 4; ++j) acc[i][j] = (f32x4){0.f, 0.f, 0.f, 0.f};

  for (int kt = 0; kt < K; kt += 32) {
    __syncthreads();
#pragma unroll
    for (int is = 0; is < 2; ++is) {
      int c = is * 256 + t;
      __builtin_amdgcn_global_load_lds(
          (gvoid*)(A + (size_t)(m0 + (c >> 2)) * K + kt + ((c & 3) << 3)),
          (lvoid*)(As + (size_t)(is * 256 + w * 64) * 8), 16, 0, 0);
      __builtin_amdgcn_global_load_lds(
          (gvoid*)(Bm + (size_t)(n0 + (c >> 2)) * K + kt + ((c & 3) << 3)),
          (lvoid*)(Bs + (size_t)(is * 256 + w * 64) * 8), 16, 0, 0);
    }
    __syncthreads();
    short8 af[4], bfr[4];
#pragma unroll
    for (int mf = 0; mf < 4; ++mf)
      af[mf] = *(const short8*)(As + (wm + mf * 16 + l16) * 32 + lhi * 8);
#pragma unroll
    for (int nf = 0; nf < 4; ++nf)
      bfr[nf] = *(const short8*)(Bs + (wn + nf * 16 + l16) * 32 + lhi * 8);
#pragma unroll
    for (int mf = 0; mf < 4; ++mf)
#pragma unroll
      for (int nf = 0; nf < 4; ++nf)
        acc[mf][nf] = __builtin_amdgcn_mfma_f32_16x16x32_bf16(
            af[mf], bfr[nf], acc[mf][nf], 0, 0, 0);
  }

#pragma unroll
  for (int mf = 0; mf < 4; ++mf)
#pragma unroll
    for (int nf = 0; nf < 4; ++nf)
#pragma unroll
      for (int i = 0; i < 4; ++i) {
        int r = m0 + wm + mf * 16 + lhi * 4 + i;
        int cc = n0 + wn + nf * 16 + l16;
        C[(size_t)r * N + cc] = acc[mf][nf][i];
      }
}

// ---------------------------------------------------------------- flash attention
// Work-balanced: 16-row q-strips; wave handles strip a and strip 127-a
// sequentially -> every wave does ~33 KV-tiles; flat occupancy.
// Grid: 64 bh x 16 groups = 1024 blocks, 4 waves each.
// K direct from global [s][dk], V direct pre-transposed [dk][s]; no barriers.
// Fixed-offset exp2 softmax; denominator via ones-column MFMA.
__global__ __launch_bounds__(256, 4) void attn_kernel(
    const unsigned short* __restrict__ Qh,
    const unsigned short* __restrict__ Kh,
    const unsigned short* __restrict__ Vt,
    unsigned short* __restrict__ O)  // bf16 [B*S, D]
{
  __shared__ unsigned short Plds[4][16 * 72];  // per-wave [q16][key64], pad 72

  int bid = blockIdx.x;
  int bh = bid & 63;            // b*H + h
  int g = bid >> 6;             // 0..15
  int t = threadIdx.x, lane = t & 63, w = t >> 6;
  int l16 = lane & 15, lhi = lane >> 4;
  int a = g * 4 + w;            // 0..63 (light strip index)

  const unsigned short* Qb = Qh + (size_t)bh * SS * DKK;
  const unsigned short* Kb = Kh + (size_t)bh * SS * DKK;
  const unsigned short* Vb = Vt + (size_t)bh * SS * DKK;  // [dk][s]
  int b = bh >> 4, h = bh & 15;

  // ones-column B fragment: column 0 is 1.0 -> row sums via MFMA
  short8 ones;
  {
    short ov = (l16 == 0) ? (short)0x3F80 : (short)0;
#pragma unroll
    for (int j = 0; j < 8; ++j) ones[j] = ov;
  }

  for (int half = 0; half < 2; ++half) {
    int strip = half ? (127 - a) : a;
    int wq0 = strip << 4;
    int nt = (wq0 >> 6) + 1;  // causal tiles of 64 keys

    // Q fragments (scores pre-scaled by 0.125*log2e in the QKV GEMM)
    short8 aq[2];
#pragma unroll
    for (int kc = 0; kc < 2; ++kc)
      aq[kc] = *(const short8*)(Qb + (size_t)(wq0 + l16) * DKK + kc * 32 + lhi * 8);

    f32x4 oacc[4], acc1;
    acc1 = (f32x4){0.f, 0.f, 0.f, 0.f};
#pragma unroll
    for (int d = 0; d < 4; ++d) oacc[d] = (f32x4){0.f, 0.f, 0.f, 0.f};

    short8 bk[4][2], bv[4][2];
#pragma unroll
    for (int sf = 0; sf < 4; ++sf)
#pragma unroll
      for (int kc = 0; kc < 2; ++kc)
        bk[sf][kc] = *(const short8*)(Kb + (size_t)(sf * 16 + l16) * DKK +
                                      kc * 32 + lhi * 8);
#pragma unroll
    for (int d = 0; d < 4; ++d)
#pragma unroll
      for (int kc = 0; kc < 2; ++kc)
        bv[d][kc] = *(const short8*)(Vb + (size_t)(d * 16 + l16) * SS +
                                     kc * 32 + lhi * 8);

    for (int tt = 0; tt < nt; ++tt) {
      int kv0 = tt << 6;
      // ---- S = Q K^T over 64 keys (16 q-rows)
      f32x4 sacc[4];
#pragma unroll
      for (int sf = 0; sf < 4; ++sf) {
        sacc[sf] = (f32x4){0.f, 0.f, 0.f, 0.f};
        sacc[sf] = __builtin_amdgcn_mfma_f32_16x16x32_bf16(
            aq[0], bk[sf][0], sacc[sf], 0, 0, 0);
        sacc[sf] = __builtin_amdgcn_mfma_f32_16x16x32_bf16(
            aq[1], bk[sf][1], sacc[sf], 0, 0, 0);
      }
      // prefetch next K tile
      if (tt + 1 < nt) {
        int nk = kv0 + 64;
#pragma unroll
        for (int sf = 0; sf < 4; ++sf)
#pragma unroll
          for (int kc = 0; kc < 2; ++kc)
            bk[sf][kc] = *(const short8*)(Kb + (size_t)(nk + sf * 16 + l16) * DKK +
                                          kc * 32 + lhi * 8);
      }
      // ---- P = 2^(s - 16), causal mask on last tile only
      bool lastT = (tt == nt - 1);
#pragma unroll
      for (int sf = 0; sf < 4; ++sf)
#pragma unroll
        for (int i = 0; i < 4; ++i) {
          float p = exp2f(sacc[sf][i] - 16.0f);
          if (lastT) {
            int key = kv0 + sf * 16 + l16;
            int qr = wq0 + lhi * 4 + i;
            if (key > qr) p = 0.f;
          }
          Plds[w][(lhi * 4 + i) * 72 + sf * 16 + l16] = f2bf(p);
        }
      // ---- PV (+ denominator via ones column)
      short8 ap[2];
#pragma unroll
      for (int kc = 0; kc < 2; ++kc)
        ap[kc] = *(const short8*)(&Plds[w][l16 * 72 + kc * 32 + lhi * 8]);
#pragma unroll
      for (int kc = 0; kc < 2; ++kc)
        acc1 = __builtin_amdgcn_mfma_f32_16x16x32_bf16(ap[kc], ones, acc1, 0, 0, 0);
#pragma unroll
      for (int d = 0; d < 4; ++d)
#pragma unroll
        for (int kc = 0; kc < 2; ++kc)
          oacc[d] = __builtin_amdgcn_mfma_f32_16x16x32_bf16(
              ap[kc], bv[d][kc], oacc[d], 0, 0, 0);
      // prefetch next V tile
      if (tt + 1 < nt) {
        int nk = kv0 + 64;
#pragma unroll
        for (int d = 0; d < 4; ++d)
#pragma unroll
          for (int kc = 0; kc < 2; ++kc)
            bv[d][kc] = *(const short8*)(Vb + (size_t)(d * 16 + l16) * SS + nk +
                                         kc * 32 + lhi * 8);
      }
    }

    // epilogue: broadcast denominator (col 0 of acc1), write attn output
#pragma unroll
    for (int i = 0; i < 4; ++i) {
      float l = __shfl(acc1[i], lane & 48);
      float inv = 1.0f / l;
      int s = wq0 + lhi * 4 + i;
#pragma unroll
      for (int d = 0; d < 4; ++d)
        O[(size_t)(b * SS + s) * DD + h * DKK + d * 16 + l16] =
            f2bf(oacc[d][i] * inv);
    }
  }
}

// ---------------------------------------------------------------- launch
extern "C" void kernel_launch(void* const* d_in, const int* in_sizes, int n_in,
                              void* d_out, int out_size, void* d_ws, size_t ws_size,
                              hipStream_t stream) {
  const float* x  = (const float*)d_in[0];
  const float* WQ = (const float*)d_in[1];
  const float* WK = (const float*)d_in[2];
  const float* WV = (const float*)d_in[3];
  const float* WO = (const float*)d_in[4];
  float* out = (float*)d_out;

  const size_t NX = (size_t)BB * SS * DD;   // 8.39M
  const size_t NW = (size_t)DD * DD;        // 1.05M

  unsigned short* xb   = (unsigned short*)d_ws;
  unsigned short* wcat = xb + NX;           // [wq|wk|wv|wo] contiguous
  unsigned short* wo   = wcat + 3 * NW;
  unsigned short* Qh   = wcat + 4 * NW;
  unsigned short* Kh   = Qh + NX;
  unsigned short* Vt   = Kh + NX;
  unsigned short* attn = Vt + NX;

  convert_f32_bf16<<<(int)(NX / 4 / 256), 256, 0, stream>>>(x, xb, (int)(NX / 4));
  convert_w4<<<dim3((unsigned)(NW / 4 / 256), 4), 256, 0, stream>>>(
      WQ, WK, WV, WO, wcat, (int)(NW / 4));

  gemm_qkv<<<64 * 24, 256, 0, stream>>>(xb, wcat, Qh, Kh, Vt);

  attn_kernel<<<BB * HH * (SS / 128), 256, 0, stream>>>(Qh, Kh, Vt, attn);

  gemm_wo<<<64 * 8, 256, 0, stream>>>(attn, wo, out, DD, DD);
}

// Round 8
// 356.351 us; speedup vs baseline: 1.3476x; 1.3476x over previous
//
#include <hip/hip_runtime.h>
#include <hip/hip_bf16.h>

// Problem constants
#define BB 4
#define SS 2048
#define DD 1024
#define HH 16
#define DKK 64

typedef __attribute__((ext_vector_type(8))) short short8;
typedef __attribute__((ext_vector_type(4))) float f32x4;

typedef const __attribute__((address_space(1))) void gvoid;
typedef __attribute__((address_space(3))) void lvoid;

__device__ __forceinline__ unsigned short f2bf(float f) {
  unsigned int u = __builtin_bit_cast(unsigned int, f);
  u = (u + 0x7FFFu + ((u >> 16) & 1u)) >> 16;
  return (unsigned short)u;
}

__device__ __forceinline__ unsigned short f2bf_hw(float f) {
  return __builtin_bit_cast(unsigned short, __float2bfloat16(f));
}

// ---------------------------------------------------------------- converts
__global__ __launch_bounds__(256) void convert_f32_bf16(
    const float* __restrict__ in, unsigned short* __restrict__ out, int n4) {
  int i = blockIdx.x * blockDim.x + threadIdx.x;
  if (i >= n4) return;
  float4 v = reinterpret_cast<const float4*>(in)[i];
  ushort4 o;
  o.x = f2bf(v.x); o.y = f2bf(v.y); o.z = f2bf(v.z); o.w = f2bf(v.w);
  reinterpret_cast<ushort4*>(out)[i] = o;
}

// 4 weight matrices -> contiguous bf16 [wq|wk|wv|wo]
__global__ __launch_bounds__(256) void convert_w4(
    const float* __restrict__ a, const float* __restrict__ b,
    const float* __restrict__ c, const float* __restrict__ d,
    unsigned short* __restrict__ out, int n4) {
  int m = blockIdx.y;
  const float* src = (m == 0) ? a : (m == 1) ? b : (m == 2) ? c : d;
  int i = blockIdx.x * blockDim.x + threadIdx.x;
  if (i >= n4) return;
  float4 v = reinterpret_cast<const float4*>(src)[i];
  ushort4 o;
  o.x = f2bf(v.x); o.y = f2bf(v.y); o.z = f2bf(v.z); o.w = f2bf(v.w);
  reinterpret_cast<ushort4*>(out)[(size_t)m * n4 + i] = o;
}

// ---------------------------------------------------------------- merged QKV GEMM
// C = x[8192,1024] * Wcat[3072,1024]^T ; n-tile selects matrix (Q/K/V).
// Q scaled by 1/sqrt(DK)*log2e, scattered to [b,h,s,dk]; K scattered to
// [b,h,s,dk]; V scattered transposed to [b,h,dk,s].
__global__ __launch_bounds__(256) void gemm_qkv(
    const unsigned short* __restrict__ A,
    const unsigned short* __restrict__ Bm,
    unsigned short* __restrict__ Qo,
    unsigned short* __restrict__ Ko,
    unsigned short* __restrict__ Vo)
{
  __shared__ unsigned short As[128 * 32];
  __shared__ unsigned short Bs[128 * 32];
  const int K = DD;
  int bid = blockIdx.x;
  int m0 = (bid / 24) << 7;
  int n0 = (bid % 24) << 7;
  int t = threadIdx.x;
  int lane = t & 63, w = t >> 6;
  int l16 = lane & 15, lhi = lane >> 4;
  int wm = (w >> 1) * 64, wn = (w & 1) * 64;

  f32x4 acc[4][4];
#pragma unroll
  for (int i = 0; i < 4; ++i)
#pragma unroll
    for (int j = 0; j < 4; ++j) acc[i][j] = (f32x4){0.f, 0.f, 0.f, 0.f};

  for (int kt = 0; kt < K; kt += 32) {
    __syncthreads();
#pragma unroll
    for (int is = 0; is < 2; ++is) {
      int c = is * 256 + t;
      __builtin_amdgcn_global_load_lds(
          (gvoid*)(A + (size_t)(m0 + (c >> 2)) * K + kt + ((c & 3) << 3)),
          (lvoid*)(As + (size_t)(is * 256 + w * 64) * 8), 16, 0, 0);
      __builtin_amdgcn_global_load_lds(
          (gvoid*)(Bm + (size_t)(n0 + (c >> 2)) * K + kt + ((c & 3) << 3)),
          (lvoid*)(Bs + (size_t)(is * 256 + w * 64) * 8), 16, 0, 0);
    }
    __syncthreads();
    short8 af[4], bfr[4];
#pragma unroll
    for (int mf = 0; mf < 4; ++mf)
      af[mf] = *(const short8*)(As + (wm + mf * 16 + l16) * 32 + lhi * 8);
#pragma unroll
    for (int nf = 0; nf < 4; ++nf)
      bfr[nf] = *(const short8*)(Bs + (wn + nf * 16 + l16) * 32 + lhi * 8);
#pragma unroll
    for (int mf = 0; mf < 4; ++mf)
#pragma unroll
      for (int nf = 0; nf < 4; ++nf)
        acc[mf][nf] = __builtin_amdgcn_mfma_f32_16x16x32_bf16(
            af[mf], bfr[nf], acc[mf][nf], 0, 0, 0);
  }

  int mat = n0 >> 10;        // 0=Q 1=K 2=V (tile never straddles: 1024%128==0)
  int nb = n0 & 1023;
  const float qscale = 0.18033688011112042f;  // 0.125 * log2(e)
#pragma unroll
  for (int mf = 0; mf < 4; ++mf)
#pragma unroll
    for (int nf = 0; nf < 4; ++nf)
#pragma unroll
      for (int i = 0; i < 4; ++i) {
        int r = m0 + wm + mf * 16 + lhi * 4 + i;
        int c1 = nb + wn + nf * 16 + l16;
        int b = r >> 11, s = r & 2047;
        int h = c1 >> 6, dk = c1 & 63;
        if (mat == 0)
          Qo[((size_t)((b * HH + h) * SS + s) << 6) + dk] =
              f2bf(acc[mf][nf][i] * qscale);
        else if (mat == 1)
          Ko[((size_t)((b * HH + h) * SS + s) << 6) + dk] = f2bf(acc[mf][nf][i]);
        else
          Vo[(size_t)((b * HH + h) * DKK + dk) * SS + s] = f2bf(acc[mf][nf][i]);
      }
}

// ---------------------------------------------------------------- WO GEMM (fp32 out)
__global__ __launch_bounds__(256) void gemm_wo(
    const unsigned short* __restrict__ A,
    const unsigned short* __restrict__ Bm,
    float* __restrict__ C, int N, int K)
{
  __shared__ unsigned short As[128 * 32];
  __shared__ unsigned short Bs[128 * 32];
  int bid = blockIdx.x;
  int ntn = N >> 7;
  int m0 = (bid / ntn) << 7;
  int n0 = (bid % ntn) << 7;
  int t = threadIdx.x;
  int lane = t & 63, w = t >> 6;
  int l16 = lane & 15, lhi = lane >> 4;
  int wm = (w >> 1) * 64, wn = (w & 1) * 64;

  f32x4 acc[4][4];
#pragma unroll
  for (int i = 0; i < 4; ++i)
#pragma unroll
    for (int j = 0; j < 4; ++j) acc[i][j] = (f32x4){0.f, 0.f, 0.f, 0.f};

  for (int kt = 0; kt < K; kt += 32) {
    __syncthreads();
#pragma unroll
    for (int is = 0; is < 2; ++is) {
      int c = is * 256 + t;
      __builtin_amdgcn_global_load_lds(
          (gvoid*)(A + (size_t)(m0 + (c >> 2)) * K + kt + ((c & 3) << 3)),
          (lvoid*)(As + (size_t)(is * 256 + w * 64) * 8), 16, 0, 0);
      __builtin_amdgcn_global_load_lds(
          (gvoid*)(Bm + (size_t)(n0 + (c >> 2)) * K + kt + ((c & 3) << 3)),
          (lvoid*)(Bs + (size_t)(is * 256 + w * 64) * 8), 16, 0, 0);
    }
    __syncthreads();
    short8 af[4], bfr[4];
#pragma unroll
    for (int mf = 0; mf < 4; ++mf)
      af[mf] = *(const short8*)(As + (wm + mf * 16 + l16) * 32 + lhi * 8);
#pragma unroll
    for (int nf = 0; nf < 4; ++nf)
      bfr[nf] = *(const short8*)(Bs + (wn + nf * 16 + l16) * 32 + lhi * 8);
#pragma unroll
    for (int mf = 0; mf < 4; ++mf)
#pragma unroll
      for (int nf = 0; nf < 4; ++nf)
        acc[mf][nf] = __builtin_amdgcn_mfma_f32_16x16x32_bf16(
            af[mf], bfr[nf], acc[mf][nf], 0, 0, 0);
  }

#pragma unroll
  for (int mf = 0; mf < 4; ++mf)
#pragma unroll
    for (int nf = 0; nf < 4; ++nf)
#pragma unroll
      for (int i = 0; i < 4; ++i) {
        int r = m0 + wm + mf * 16 + lhi * 4 + i;
        int cc = n0 + wn + nf * 16 + l16;
        C[(size_t)r * N + cc] = acc[mf][nf][i];
      }
}

// ---------------------------------------------------------------- flash attention
// (round-6 structure: measured 142.7us) Grid: 1024 blocks (bh inner 64,
// q-block outer heavy-first), 256 threads = 4 independent waves x 32 q-rows.
// KV tile 64. K direct from global [s][dk], V direct pre-transposed [dk][s].
// No barriers, no K/V LDS. Fixed-offset exp2 softmax, denominator via
// ones-column MFMA. P exchanged through per-wave padded LDS.
__global__ __launch_bounds__(256, 2) void attn_kernel(
    const unsigned short* __restrict__ Qh,
    const unsigned short* __restrict__ Kh,
    const unsigned short* __restrict__ Vt,
    unsigned short* __restrict__ O)  // bf16 [B*S, D]
{
  __shared__ unsigned short Plds[4][32 * 72];  // per-wave [q][key], pad 72

  int bid = blockIdx.x;
  int bh = bid & 63;            // b*H + h
  int qb = 15 - (bid >> 6);     // heavy q-blocks scheduled first
  int q0 = qb << 7;
  int t = threadIdx.x, lane = t & 63, w = t >> 6;
  int l16 = lane & 15, lhi = lane >> 4;
  int wq0 = q0 + w * 32;

  const unsigned short* Qb = Qh + (size_t)bh * SS * DKK;
  const unsigned short* Kb = Kh + (size_t)bh * SS * DKK;
  const unsigned short* Vb = Vt + (size_t)bh * SS * DKK;  // [dk][s]

  // Q fragments (scores already scaled by 0.125*log2e via GEMM)
  short8 aq[2][2];
#pragma unroll
  for (int qf = 0; qf < 2; ++qf)
#pragma unroll
    for (int kc = 0; kc < 2; ++kc)
      aq[qf][kc] = *(const short8*)(Qb + (size_t)(wq0 + qf * 16 + l16) * DKK +
                                    kc * 32 + lhi * 8);

  f32x4 oacc[2][4], acc1[2];
#pragma unroll
  for (int qf = 0; qf < 2; ++qf) {
    acc1[qf] = (f32x4){0.f, 0.f, 0.f, 0.f};
#pragma unroll
    for (int d = 0; d < 4; ++d) oacc[qf][d] = (f32x4){0.f, 0.f, 0.f, 0.f};
  }

  // ones-column B fragment: column n==0 is 1.0, rest 0 -> row sums
  short8 ones;
  {
    short ov = (l16 == 0) ? (short)0x3F80 : (short)0;
#pragma unroll
    for (int j = 0; j < 8; ++j) ones[j] = ov;
  }

  int nt = (wq0 >> 6) + 1;  // causal: tiles of 64 keys

  short8 bk[4][2], bv[4][2];
#pragma unroll
  for (int sf = 0; sf < 4; ++sf)
#pragma unroll
    for (int kc = 0; kc < 2; ++kc)
      bk[sf][kc] = *(const short8*)(Kb + (size_t)(sf * 16 + l16) * DKK +
                                    kc * 32 + lhi * 8);
#pragma unroll
  for (int d = 0; d < 4; ++d)
#pragma unroll
    for (int kc = 0; kc < 2; ++kc)
      bv[d][kc] = *(const short8*)(Vb + (size_t)(d * 16 + l16) * SS +
                                   kc * 32 + lhi * 8);

  for (int tt = 0; tt < nt; ++tt) {
    int kv0 = tt << 6;
    // ---- S = Q K^T over 64 keys
    f32x4 sacc[2][4];
#pragma unroll
    for (int qf = 0; qf < 2; ++qf)
#pragma unroll
      for (int sf = 0; sf < 4; ++sf) {
        sacc[qf][sf] = (f32x4){0.f, 0.f, 0.f, 0.f};
        sacc[qf][sf] = __builtin_amdgcn_mfma_f32_16x16x32_bf16(
            aq[qf][0], bk[sf][0], sacc[qf][sf], 0, 0, 0);
        sacc[qf][sf] = __builtin_amdgcn_mfma_f32_16x16x32_bf16(
            aq[qf][1], bk[sf][1], sacc[qf][sf], 0, 0, 0);
      }
    // prefetch next K tile (latency covered by exp2 + P + PV below)
    if (tt + 1 < nt) {
      int nk = kv0 + 64;
#pragma unroll
      for (int sf = 0; sf < 4; ++sf)
#pragma unroll
        for (int kc = 0; kc < 2; ++kc)
          bk[sf][kc] = *(const short8*)(Kb + (size_t)(nk + sf * 16 + l16) * DKK +
                                        kc * 32 + lhi * 8);
    }
    // ---- P = 2^(s - 16), causal mask on last tile only
    bool lastT = (tt == nt - 1);
#pragma unroll
    for (int qf = 0; qf < 2; ++qf)
#pragma unroll
      for (int sf = 0; sf < 4; ++sf)
#pragma unroll
        for (int i = 0; i < 4; ++i) {
          float p = exp2f(sacc[qf][sf][i] - 16.0f);
          if (lastT) {
            int key = kv0 + sf * 16 + l16;
            int qr = wq0 + qf * 16 + lhi * 4 + i;
            if (key > qr) p = 0.f;
          }
          Plds[w][(qf * 16 + lhi * 4 + i) * 72 + sf * 16 + l16] = f2bf_hw(p);
        }
    // ---- PV (+ denominator via ones column)
    short8 ap[2][2];
#pragma unroll
    for (int qf = 0; qf < 2; ++qf)
#pragma unroll
      for (int kc = 0; kc < 2; ++kc)
        ap[qf][kc] = *(const short8*)(&Plds[w][(qf * 16 + l16) * 72 + kc * 32 + lhi * 8]);
#pragma unroll
    for (int qf = 0; qf < 2; ++qf)
#pragma unroll
      for (int kc = 0; kc < 2; ++kc)
        acc1[qf] = __builtin_amdgcn_mfma_f32_16x16x32_bf16(
            ap[qf][kc], ones, acc1[qf], 0, 0, 0);
#pragma unroll
    for (int qf = 0; qf < 2; ++qf)
#pragma unroll
      for (int d = 0; d < 4; ++d)
#pragma unroll
        for (int kc = 0; kc < 2; ++kc)
          oacc[qf][d] = __builtin_amdgcn_mfma_f32_16x16x32_bf16(
              ap[qf][kc], bv[d][kc], oacc[qf][d], 0, 0, 0);
    // prefetch next V tile
    if (tt + 1 < nt) {
      int nk = kv0 + 64;
#pragma unroll
      for (int d = 0; d < 4; ++d)
#pragma unroll
        for (int kc = 0; kc < 2; ++kc)
          bv[d][kc] = *(const short8*)(Vb + (size_t)(d * 16 + l16) * SS + nk +
                                       kc * 32 + lhi * 8);
    }
  }

  // epilogue: broadcast denominator (col 0 of acc1) and write attn output
  int b = bh >> 4, h = bh & 15;
#pragma unroll
  for (int qf = 0; qf < 2; ++qf)
#pragma unroll
    for (int i = 0; i < 4; ++i) {
      float l = __shfl(acc1[qf][i], lane & 48);
      float inv = 1.0f / l;
      int s = wq0 + qf * 16 + lhi * 4 + i;
#pragma unroll
      for (int d = 0; d < 4; ++d)
        O[(size_t)(b * SS + s) * DD + h * DKK + d * 16 + l16] =
            f2bf(oacc[qf][d][i] * inv);
    }
}

// ---------------------------------------------------------------- launch
extern "C" void kernel_launch(void* const* d_in, const int* in_sizes, int n_in,
                              void* d_out, int out_size, void* d_ws, size_t ws_size,
                              hipStream_t stream) {
  const float* x  = (const float*)d_in[0];
  const float* WQ = (const float*)d_in[1];
  const float* WK = (const float*)d_in[2];
  const float* WV = (const float*)d_in[3];
  const float* WO = (const float*)d_in[4];
  float* out = (float*)d_out;

  const size_t NX = (size_t)BB * SS * DD;   // 8.39M
  const size_t NW = (size_t)DD * DD;        // 1.05M

  unsigned short* xb   = (unsigned short*)d_ws;
  unsigned short* wcat = xb + NX;           // [wq|wk|wv|wo] contiguous
  unsigned short* wo   = wcat + 3 * NW;
  unsigned short* Qh   = wcat + 4 * NW;
  unsigned short* Kh   = Qh + NX;
  unsigned short* Vt   = Kh + NX;
  unsigned short* attn = Vt + NX;

  convert_f32_bf16<<<(int)(NX / 4 / 256), 256, 0, stream>>>(x, xb, (int)(NX / 4));
  convert_w4<<<dim3((unsigned)(NW / 4 / 256), 4), 256, 0, stream>>>(
      WQ, WK, WV, WO, wcat, (int)(NW / 4));

  gemm_qkv<<<64 * 24, 256, 0, stream>>>(xb, wcat, Qh, Kh, Vt);

  attn_kernel<<<BB * HH * (SS / 128), 256, 0, stream>>>(Qh, Kh, Vt, attn);

  gemm_wo<<<64 * 8, 256, 0, stream>>>(attn, wo, out, DD, DD);
}